// Round 14
// baseline (850.454 us; speedup 1.0000x reference)
//
#include <hip/hip_runtime.h>
#include <hip/hip_bf16.h>
#include <math.h>

#define N_NODES 50000
#define N_PAD   50048   // 391 * 128
#define N_EDGES 800000
#define HEADS 4

typedef __attribute__((ext_vector_type(8))) _Float16 half8_t;
typedef __attribute__((ext_vector_type(4))) _Float16 half4_t;
typedef __attribute__((ext_vector_type(4))) float f32x4;

// 2-way f16 split: v ~= (float)p0 + (float)p1, exact to ~2^-23 relative.
__device__ inline void split2(float v, _Float16& p0, _Float16& p1) {
    p0 = (_Float16)v;
    p1 = (_Float16)(v - (float)p0);
}

// Swizzled k-tiled plane layout (A and W planes):
//   elem (row, k) at  (k>>5)*rows*32 + row*32 + ((((k>>3)&3) ^ (row&3))<<3) + (k&7)
// XOR bakes the LDS bank-swizzle into global memory; for direct-from-L2 B
// fragment reads the same pattern is a coalesced 1KB wave-read.

// ---------------------------------------------------------------------------
// CSR construction
// ---------------------------------------------------------------------------

__global__ void init_deg_kernel(int* __restrict__ deg) {
    int i = blockIdx.x * blockDim.x + threadIdx.x;
    if (i < N_NODES) deg[i] = 1;  // self-loop
}

__global__ void hist_kernel(const int* __restrict__ dst, int* __restrict__ deg) {
    int i = blockIdx.x * blockDim.x + threadIdx.x;
    if (i < N_EDGES) atomicAdd(&deg[dst[i]], 1);
}

// Wave-coalesced two-phase scan (16 waves, contiguous chunks).
__global__ __launch_bounds__(1024) void scan_kernel(const int* __restrict__ deg,
                                                    int* __restrict__ rowptr,
                                                    int* __restrict__ cursor) {
    __shared__ int wsums[16];
    const int t = threadIdx.x;
    const int wv = t >> 6, ln = t & 63;
    const int WCHUNK = (N_NODES + 15) / 16;   // 3125
    const int base = wv * WCHUNK;
    int lim = base + WCHUNK; if (lim > N_NODES) lim = N_NODES;

    int tot = 0;
    for (int i = base + ln; i < lim; i += 64) tot += deg[i];
#pragma unroll
    for (int o = 1; o < 64; o <<= 1) tot += __shfl_xor(tot, o);
    if (ln == 0) wsums[wv] = tot;
    __syncthreads();

    int run = 0;
    for (int w = 0; w < wv; ++w) run += wsums[w];

    for (int i0 = base; i0 < lim; i0 += 64) {
        int i = i0 + ln;
        int d = (i < lim) ? deg[i] : 0;
        int sc = d;
#pragma unroll
        for (int o = 1; o < 64; o <<= 1) {
            int v = __shfl_up(sc, o);
            if (ln >= o) sc += v;
        }
        if (i < lim) {
            int val = run + sc - d;
            rowptr[i] = val;
            cursor[i] = val;
        }
        run += __shfl(sc, 63);
    }
    if (t == 1023) rowptr[N_NODES] = run;
}

__global__ void scatter_kernel(const int* __restrict__ src, const int* __restrict__ dst,
                               int* __restrict__ cursor, int* __restrict__ col) {
    int i = blockIdx.x * blockDim.x + threadIdx.x;
    if (i < N_EDGES) {
        int d = dst[i];
        int pos = atomicAdd(&cursor[d], 1);
        col[pos] = src[i];
    } else if (i < N_EDGES + N_NODES) {
        int n = i - N_EDGES;
        int pos = atomicAdd(&cursor[n], 1);
        col[pos] = n;
    }
}

// ---------------------------------------------------------------------------
// Splitters -> swizzled k-tiled planes
// ---------------------------------------------------------------------------

__global__ void x_split_kernel(const float* __restrict__ x, _Float16* __restrict__ pl,
                               size_t pstride) {
    int i = blockIdx.x * blockDim.x + threadIdx.x;
    if (i >= N_NODES * 64) return;
    int n = i >> 6, k = i & 63;
    _Float16 a, b;
    split2(x[i], a, b);
    size_t off = (size_t)(k >> 5) * ((size_t)N_PAD * 32) + (size_t)n * 32 +
                 ((((k >> 3) & 3) ^ (n & 3)) << 3) + (k & 7);
    pl[off] = a;
    pl[pstride + off] = b;
}

struct W5 { const float* p[5]; };

// all 5 layers in one launch: t = l*65536 + c*256 + k
__global__ void w_split_kernel(W5 ws, _Float16* __restrict__ wt) {
    int t = blockIdx.x * blockDim.x + threadIdx.x;
    int l = t >> 16;
    int r = t & 65535;
    int c = r >> 8, k = r & 255;
    int K = (l == 0) ? 64 : 256;
    int NC = (l == 4) ? 40 : 256;
    float v = (k < K && c < NC) ? ws.p[l][k * NC + c] : 0.f;
    _Float16 a, b;
    split2(v, a, b);
    size_t off = (size_t)l * 131072 +
                 (size_t)(k >> 5) * 8192 + (size_t)c * 32 +
                 ((((k >> 3) & 3) ^ (c & 3)) << 3) + (k & 7);
    wt[off] = a;
    wt[65536 + off] = b;
}

// ---------------------------------------------------------------------------
// f16x2 MFMA GEMM: A double-buffered via global_load_lds (16KB/tile, 32KB
// LDS total), B fragments DIRECT from L2 (weight planes L2-resident; the
// k-tiled layout makes each fragment a coalesced 1KB wave-read).
// NOTE round-12 bug was the missing n0 term in the B base pointer — fixed.
// One barrier per k-tile; next-tile A loads issued before compute.
// FUSE_ATTN=1 (layers 0-3): C = f32 h [N][256] + fused asn/adn epilogue.
// FUSE_ATTN=0 (layer 4):   C = f32 [N][NC]; waves with cols >= NC skip MFMA.
// 3 MFMAs per (i,j): a0b0 + a0b1 + a1b0  (a1b1 ~ 2^-22, dropped).
// ---------------------------------------------------------------------------

template <int FUSE_ATTN>
__global__ __launch_bounds__(256) void gemm_mfma_kernel(
        const _Float16* __restrict__ Apl, size_t apstride,
        const _Float16* __restrict__ Wt,   // swizzled k-tiled [2][kt][256][32]
        float* __restrict__ C, int K, int NC,
        const float* __restrict__ as_flat, const float* __restrict__ ad_flat,
        float* __restrict__ asn, float* __restrict__ adn) {
    __shared__ __align__(16) _Float16 lds[2][8192];   // 2 x 16KB (A only)

    const int tid = threadIdx.x;
    const int lane = tid & 63;
    const int wave = tid >> 6;
    const int wr = (wave >> 1) * 64;
    const int wc = (wave & 1) * 64;
    const int m0 = blockIdx.x * 128;
    const int n0 = blockIdx.y * 128;
    const bool wave_active = FUSE_ATTN ? true : ((n0 + wc) < NC);

    f32x4 acc[4][4];
#pragma unroll
    for (int i = 0; i < 4; ++i)
#pragma unroll
        for (int j = 0; j < 4; ++j) acc[i][j] = (f32x4){0.f, 0.f, 0.f, 0.f};

    // A staging: 16 chunks of 1KB per tile; wave handles chunks [wave*4, +4).
    // Global src has per-lane +lane*8 elems; LDS dest is wave-uniform (the
    // hardware adds lane*16 bytes itself).
    const size_t ktstep = (size_t)N_PAD * 32;
    const _Float16* agsrc[4];
    unsigned ldoff[4];   // wave-uniform byte offsets
#pragma unroll
    for (int it = 0; it < 4; ++it) {
        int c = wave * 4 + it;
        int p = c >> 3, idx = c & 7;
        agsrc[it] = Apl + (size_t)p * apstride + (size_t)m0 * 32 + idx * 512 + lane * 8;
        ldoff[it] = (unsigned)(p * 8192 + idx * 1024);   // bytes, uniform
    }

    const int cswz = ((lane >> 4) ^ (lane & 3)) << 3;   // elems
    // B fragment base: global col = n0 + wc + j*16 + (lane&15)   [n0 FIX]
    const _Float16* bfb = Wt + (size_t)(n0 + wc + (lane & 15)) * 32 + cswz;
    const int KT = K >> 5;

    // prologue: stage A tile 0 into buf 0
#pragma unroll
    for (int it = 0; it < 4; ++it) {
        __builtin_amdgcn_global_load_lds(
            (const __attribute__((address_space(1))) void*)agsrc[it],
            (__attribute__((address_space(3))) void*)((char*)&lds[0][0] + ldoff[it]),
            16, 0, 0);
    }

    for (int kt = 0; kt < KT; ++kt) {
        __syncthreads();   // my in-flight A loads drained; prev buf free

        if (kt + 1 < KT) {
            char* dstw = (char*)&lds[(kt + 1) & 1][0];
#pragma unroll
            for (int it = 0; it < 4; ++it) {
                __builtin_amdgcn_global_load_lds(
                    (const __attribute__((address_space(1))) void*)(agsrc[it] + (size_t)(kt + 1) * ktstep),
                    (__attribute__((address_space(3))) void*)(dstw + ldoff[it]),
                    16, 0, 0);
            }
        }

        if (wave_active) {
            // B fragments direct from L2 (coalesced 1KB per fragment)
            half8_t bf[2][4];
#pragma unroll
            for (int p = 0; p < 2; ++p)
#pragma unroll
                for (int j = 0; j < 4; ++j)
                    bf[p][j] = *(const half8_t*)(bfb + p * 65536 + (size_t)kt * 8192 + j * 512);

            const _Float16* Ab = &lds[kt & 1][0];
#pragma unroll
            for (int i = 0; i < 4; ++i) {
                int r = wr + i * 16 + (lane & 15);
                half8_t af0 = *(const half8_t*)(Ab + r * 32 + cswz);
                half8_t af1 = *(const half8_t*)(Ab + 4096 + r * 32 + cswz);
#pragma unroll
                for (int j = 0; j < 4; ++j) {
                    f32x4 c = acc[i][j];
                    c = __builtin_amdgcn_mfma_f32_16x16x32_f16(af0, bf[1][j], c, 0, 0, 0);
                    c = __builtin_amdgcn_mfma_f32_16x16x32_f16(af1, bf[0][j], c, 0, 0, 0);
                    c = __builtin_amdgcn_mfma_f32_16x16x32_f16(af0, bf[0][j], c, 0, 0, 0);
                    acc[i][j] = c;
                }
            }
        }
    }

    // epilogue: C/D mapping col = lane&15, row = (lane>>4)*4 + reg
    const int rbase = m0 + wr + (lane >> 4) * 4;
    const int cbase = n0 + wc + (lane & 15);

    if (FUSE_ATTN) {
        // h -> f32 [N][256]
#pragma unroll
        for (int i = 0; i < 4; ++i)
#pragma unroll
            for (int j = 0; j < 4; ++j) {
                int gcol = cbase + j * 16;
#pragma unroll
                for (int r4 = 0; r4 < 4; ++r4) {
                    int grow = rbase + i * 16 + r4;
                    if (grow < N_NODES) C[(size_t)grow * 256 + gcol] = acc[i][j][r4];
                }
            }
        // fused asn/adn: this wave's 64 cols == head (n0+wc)>>6 (CH=64)
        const int hd_out = (n0 + wc) >> 6;
        float as_v[4], ad_v[4];
#pragma unroll
        for (int j = 0; j < 4; ++j) {
            int gc = cbase + j * 16;
            as_v[j] = as_flat[gc];
            ad_v[j] = ad_flat[gc];
        }
#pragma unroll
        for (int i = 0; i < 4; ++i)
#pragma unroll
            for (int r4 = 0; r4 < 4; ++r4) {
                float ps = 0.f, pd = 0.f;
#pragma unroll
                for (int j = 0; j < 4; ++j) {
                    float v = acc[i][j][r4];
                    ps += v * as_v[j];
                    pd += v * ad_v[j];
                }
#pragma unroll
                for (int o = 1; o < 16; o <<= 1) {
                    ps += __shfl_xor(ps, o);
                    pd += __shfl_xor(pd, o);
                }
                if ((lane & 15) == 0) {
                    int grow = rbase + i * 16 + r4;
                    if (grow < N_NODES) {
                        asn[grow * 4 + hd_out] = ps;
                        adn[grow * 4 + hd_out] = pd;
                    }
                }
            }
    } else {
#pragma unroll
        for (int i = 0; i < 4; ++i)
#pragma unroll
            for (int j = 0; j < 4; ++j) {
                int gcol = cbase + j * 16;
                if (gcol >= NC) continue;
#pragma unroll
                for (int r4 = 0; r4 < 4; ++r4) {
                    int grow = rbase + i * 16 + r4;
                    if (grow < N_NODES) C[(size_t)grow * NC + gcol] = acc[i][j][r4];
                }
            }
    }
}

// ---------------------------------------------------------------------------
// Standalone attention coefficients (layer 4 only, CH=10)
// ---------------------------------------------------------------------------

__global__ void attn_coef_kernel(const float* __restrict__ h,
                                 const float* __restrict__ a_s,
                                 const float* __restrict__ a_d,
                                 float* __restrict__ asn, float* __restrict__ adn,
                                 int CH) {
    int t = blockIdx.x * blockDim.x + threadIdx.x;
    if (t >= N_NODES * HEADS) return;
    int n = t >> 2;
    int hd = t & 3;
    const float* hp = h + (size_t)n * HEADS * CH + hd * CH;
    const float* sp = a_s + hd * CH;
    const float* dp = a_d + hd * CH;
    float s1 = 0.f, s2 = 0.f;
    for (int c = 0; c < CH; c += 2) {
        float2 hv = *reinterpret_cast<const float2*>(&hp[c]);
        float2 av = *reinterpret_cast<const float2*>(&sp[c]);
        float2 dv = *reinterpret_cast<const float2*>(&dp[c]);
        s1 += hv.x * av.x + hv.y * av.y;
        s2 += hv.x * dv.x + hv.y * dv.y;
    }
    asn[t] = s1;
    adn[t] = s2;
}

// ---------------------------------------------------------------------------
// One-wave-per-node aggregation (CH=64 layers): lane = 4-channel block of the
// 256-col row; one float4 per lane per edge (1KB coalesced wave-read, f32 h).
// Per-head softmax in 16-lane groups; p/src broadcast via shfl.
// Emits the next GEMM's A in swizzled k-tiled f16x2 layout.
// ---------------------------------------------------------------------------

__global__ __launch_bounds__(256) void aggregate64_kernel(
        const float* __restrict__ h,   // [N][256] f32
        const float* __restrict__ asn, const float* __restrict__ adn,
        const int* __restrict__ rowptr, const int* __restrict__ col,
        const float* __restrict__ bias,
        _Float16* __restrict__ pl, size_t pstride) {
    const int n = (blockIdx.x << 2) + (threadIdx.x >> 6);
    const int lane = threadIdx.x & 63;
    const int hd = lane >> 4;
    const int e16 = lane & 15;
    const int pbase = lane & 48;

    const int start = rowptr[n];
    const int end = rowptr[n + 1];
    const float adv = adn[(n << 2) | hd];

    float m = -INFINITY, s = 0.f;
    float a0 = 0.f, a1 = 0.f, a2 = 0.f, a3 = 0.f;

    for (int e0 = start; e0 < end; e0 += 16) {
        int e = e0 + e16;
        int srcl = n;
        float ev = -INFINITY;
        if (e < end) {
            srcl = col[e];
            float t = asn[(srcl << 2) | hd] + adv;
            ev = (t > 0.f) ? t : 0.2f * t;   // leaky_relu(0.2)
        }
        float bm = ev;
#pragma unroll
        for (int o = 1; o < 16; o <<= 1) bm = fmaxf(bm, __shfl_xor(bm, o));
        float mn = fmaxf(m, bm);
        float scale = __expf(m - mn);
        float p = __expf(ev - mn);
        float ps = p;
#pragma unroll
        for (int o = 1; o < 16; o <<= 1) ps += __shfl_xor(ps, o);
        s = s * scale + ps;
        a0 *= scale; a1 *= scale; a2 *= scale; a3 *= scale;
        m = mn;

        int cnt = end - e0; if (cnt > 16) cnt = 16;
        int cnt4 = (cnt + 3) & ~3;
        for (int j0 = 0; j0 < cnt4; j0 += 4) {
            int sj[4]; float pj[4];
#pragma unroll
            for (int j = 0; j < 4; ++j) {
                sj[j] = __shfl(srcl, j0 + j);
                pj[j] = __shfl(p, pbase + j0 + j);
            }
            float4 hv[4];
#pragma unroll
            for (int j = 0; j < 4; ++j)
                hv[j] = *reinterpret_cast<const float4*>(h + (size_t)sj[j] * 256 + (lane << 2));
#pragma unroll
            for (int j = 0; j < 4; ++j) {
                a0 += pj[j] * hv[j].x;
                a1 += pj[j] * hv[j].y;
                a2 += pj[j] * hv[j].z;
                a3 += pj[j] * hv[j].w;
            }
        }
    }

    float sd = s + 1e-16f;
    const float* bp = bias + (lane << 2);
    float v0 = fmaxf(a0 / sd + bp[0], 0.f);
    float v1 = fmaxf(a1 / sd + bp[1], 0.f);
    float v2 = fmaxf(a2 / sd + bp[2], 0.f);
    float v3 = fmaxf(a3 / sd + bp[3], 0.f);

    _Float16 s0a, s0b, s1a, s1b, s2a, s2b, s3a, s3b;
    split2(v0, s0a, s0b);
    split2(v1, s1a, s1b);
    split2(v2, s2a, s2b);
    split2(v3, s3a, s3b);
    half4_t o0, o1;
    o0[0] = s0a; o0[1] = s1a; o0[2] = s2a; o0[3] = s3a;
    o1[0] = s0b; o1[1] = s1b; o1[2] = s2b; o1[3] = s3b;

    // swizzled k-tiled emit: k = lane*4..+3
    const int kt = lane >> 3;
    const int cp = ((lane >> 1) & 3) ^ (n & 3);
    const int inner = (lane & 1) << 2;
    size_t off = (size_t)kt * ((size_t)N_PAD * 32) + (size_t)n * 32 + (cp << 3) + inner;
    *(half4_t*)(pl + off) = o0;
    *(half4_t*)(pl + pstride + off) = o1;
}

// ---------------------------------------------------------------------------
// Layer-4 aggregation (CH=10): one wave per node. Lanes 0..39 gather the
// whole 160B h-row per edge; softmax per head in 16-lane groups; p routed
// to channel lanes via shfl. Writes d_out.
// ---------------------------------------------------------------------------

__global__ __launch_bounds__(256) void aggregate_out10_kernel(
        const float* __restrict__ h,   // [N][40] f32
        const float* __restrict__ asn, const float* __restrict__ adn,
        const int* __restrict__ rowptr, const int* __restrict__ col,
        const float* __restrict__ bias, float* __restrict__ out) {
    const int n = (blockIdx.x << 2) + (threadIdx.x >> 6);
    const int lane = threadIdx.x & 63;
    const int hd16 = lane >> 4;          // softmax-role head
    const int e16 = lane & 15;
    const bool cvalid = lane < 40;
    const int hc = ((cvalid ? lane : 0) * 205) >> 11;   // lane/10: channel head

    const int start = rowptr[n];
    const int end = rowptr[n + 1];
    const float adv = adn[(n << 2) | hd16];

    float m = -INFINITY, s = 0.f, a0 = 0.f, a1 = 0.f;

    for (int e0 = start; e0 < end; e0 += 16) {
        int e = e0 + e16;
        int srcl = n;
        float ev = -INFINITY;
        if (e < end) {
            srcl = col[e];
            float t = asn[(srcl << 2) | hd16] + adv;
            ev = (t > 0.f) ? t : 0.2f * t;
        }
        float bm = ev;
#pragma unroll
        for (int o = 1; o < 16; o <<= 1) bm = fmaxf(bm, __shfl_xor(bm, o));
        float mn = fmaxf(m, bm);
        float scale = __expf(m - mn);
        float p = __expf(ev - mn);
        float ps = p;
#pragma unroll
        for (int o = 1; o < 16; o <<= 1) ps += __shfl_xor(ps, o);
        s = s * scale + ps;
        m = mn;

        float sc_c = __shfl(scale, hc * 16);   // my channel-head's scale
        a0 *= sc_c;
        a1 *= sc_c;

        int cnt = end - e0; if (cnt > 16) cnt = 16;
        int cnt4 = (cnt + 3) & ~3;
        for (int j0 = 0; j0 < cnt4; j0 += 4) {
            int sj[4]; float pj[4];
#pragma unroll
            for (int j = 0; j < 4; ++j) {
                sj[j] = __shfl(srcl, j0 + j);
                pj[j] = __shfl(p, hc * 16 + j0 + j);
            }
            float hv[4];
#pragma unroll
            for (int j = 0; j < 4; ++j)
                hv[j] = cvalid ? h[(size_t)sj[j] * 40 + lane] : 0.f;
            a0 += pj[0] * hv[0];
            a1 += pj[1] * hv[1];
            a0 += pj[2] * hv[2];
            a1 += pj[3] * hv[3];
        }
    }

    float sd = __shfl(s, hc * 16) + 1e-16f;
    if (cvalid) {
        float v = (a0 + a1) / sd + bias[lane];
        out[(size_t)n * 40 + lane] = fmaxf(v, 0.f);
    }
}

// ---------------------------------------------------------------------------

extern "C" void kernel_launch(void* const* d_in, const int* in_sizes, int n_in,
                              void* d_out, int out_size, void* d_ws, size_t ws_size,
                              hipStream_t stream) {
    const float* x_in = (const float*)d_in[0];
    const int* ei = (const int*)d_in[1];
    const int* src = ei;
    const int* dst = ei + N_EDGES;

    const float *AS[5], *AD[5], *BI[5];
    W5 w5;
    for (int l = 0; l < 5; ++l) {
        w5.p[l] = (const float*)d_in[2 + l * 4 + 0];
        AS[l] = (const float*)d_in[2 + l * 4 + 1];
        AD[l] = (const float*)d_in[2 + l * 4 + 2];
        BI[l] = (const float*)d_in[2 + l * 4 + 3];
    }

    // workspace carve-up
    const size_t PSTRIDE = (size_t)N_PAD * 256;           // elements per plane
    _Float16* planes = (_Float16*)d_ws;                   // GEMM A planes (2, swizzled k-tiled)
    float* hbuf = (float*)(planes + 2 * PSTRIDE);         // h f32 [N][256] (layer4: [N][40])
    float* asn  = hbuf + (size_t)N_NODES * 256;
    float* adn  = asn + (size_t)N_NODES * HEADS;
    int* rowptr = (int*)(adn + (size_t)N_NODES * HEADS);  // N+1
    int* cursor = rowptr + (N_NODES + 1);
    int* col    = cursor + N_NODES;                       // E + N
    _Float16* wt = (_Float16*)(((uintptr_t)(col + N_EDGES + N_NODES) + 15) & ~(uintptr_t)15);

    // --- CSR build ---
    init_deg_kernel<<<(N_NODES + 255) / 256, 256, 0, stream>>>(cursor);
    hist_kernel<<<(N_EDGES + 255) / 256, 256, 0, stream>>>(dst, cursor);
    scan_kernel<<<1, 1024, 0, stream>>>(cursor, rowptr, cursor);
    scatter_kernel<<<(N_EDGES + N_NODES + 255) / 256, 256, 0, stream>>>(src, dst, cursor, col);

    // --- weight & input splits (swizzled k-tiled) ---
    w_split_kernel<<<5 * 65536 / 256, 256, 0, stream>>>(w5, wt);
    x_split_kernel<<<(N_NODES * 64 + 255) / 256, 256, 0, stream>>>(x_in, planes, PSTRIDE);

    // --- 5 GAT layers ---
    for (int l = 0; l < 5; ++l) {
        const int K = (l == 0) ? 64 : 256;
        const int NC = (l == 4) ? 40 : 256;
        dim3 ggrid(N_PAD / 128, (NC + 127) / 128);
        const _Float16* wl = wt + (size_t)l * 131072;
        if (l < 4) {
            gemm_mfma_kernel<1><<<ggrid, 256, 0, stream>>>(
                planes, PSTRIDE, wl, hbuf, K, NC, AS[l], AD[l], asn, adn);
            aggregate64_kernel<<<N_NODES / 4, 256, 0, stream>>>(
                hbuf, asn, adn, rowptr, col, BI[l], planes, PSTRIDE);
        } else {
            gemm_mfma_kernel<0><<<ggrid, 256, 0, stream>>>(
                planes, PSTRIDE, wl, hbuf, K, NC, AS[l], AD[l], asn, adn);
            attn_coef_kernel<<<(N_NODES * HEADS + 255) / 256, 256, 0, stream>>>(
                hbuf, AS[l], AD[l], asn, adn, 10);
            aggregate_out10_kernel<<<N_NODES / 4, 256, 0, stream>>>(
                hbuf, asn, adn, rowptr, col, BI[l], (float*)d_out);
        }
    }
    (void)in_sizes; (void)n_in; (void)out_size; (void)ws_size;
}

// Round 15
// 847.189 us; speedup vs baseline: 1.0039x; 1.0039x over previous
//
#include <hip/hip_runtime.h>
#include <hip/hip_bf16.h>
#include <math.h>

#define N_NODES 50000
#define N_PAD   50048   // 391 * 128
#define N_EDGES 800000
#define HEADS 4

typedef __attribute__((ext_vector_type(8))) _Float16 half8_t;
typedef __attribute__((ext_vector_type(4))) _Float16 half4_t;
typedef __attribute__((ext_vector_type(4))) float f32x4;

// 2-way f16 split: v ~= (float)p0 + (float)p1, exact to ~2^-23 relative.
__device__ inline void split2(float v, _Float16& p0, _Float16& p1) {
    p0 = (_Float16)v;
    p1 = (_Float16)(v - (float)p0);
}

// Swizzled k-tiled plane layout (A and W planes, staged via global_load_lds):
//   elem (row, k) at  (k>>5)*rows*32 + row*32 + ((((k>>3)&3) ^ (row&3))<<3) + (k&7)

// ---------------------------------------------------------------------------
// CSR construction
// ---------------------------------------------------------------------------

__global__ void init_deg_kernel(int* __restrict__ deg) {
    int i = blockIdx.x * blockDim.x + threadIdx.x;
    if (i < N_NODES) deg[i] = 1;  // self-loop
}

__global__ void hist_kernel(const int* __restrict__ dst, int* __restrict__ deg) {
    int i = blockIdx.x * blockDim.x + threadIdx.x;
    if (i < N_EDGES) atomicAdd(&deg[dst[i]], 1);
}

// Wave-coalesced two-phase scan (16 waves, contiguous chunks).
__global__ __launch_bounds__(1024) void scan_kernel(const int* __restrict__ deg,
                                                    int* __restrict__ rowptr,
                                                    int* __restrict__ cursor) {
    __shared__ int wsums[16];
    const int t = threadIdx.x;
    const int wv = t >> 6, ln = t & 63;
    const int WCHUNK = (N_NODES + 15) / 16;   // 3125
    const int base = wv * WCHUNK;
    int lim = base + WCHUNK; if (lim > N_NODES) lim = N_NODES;

    int tot = 0;
    for (int i = base + ln; i < lim; i += 64) tot += deg[i];
#pragma unroll
    for (int o = 1; o < 64; o <<= 1) tot += __shfl_xor(tot, o);
    if (ln == 0) wsums[wv] = tot;
    __syncthreads();

    int run = 0;
    for (int w = 0; w < wv; ++w) run += wsums[w];

    for (int i0 = base; i0 < lim; i0 += 64) {
        int i = i0 + ln;
        int d = (i < lim) ? deg[i] : 0;
        int sc = d;
#pragma unroll
        for (int o = 1; o < 64; o <<= 1) {
            int v = __shfl_up(sc, o);
            if (ln >= o) sc += v;
        }
        if (i < lim) {
            int val = run + sc - d;
            rowptr[i] = val;
            cursor[i] = val;
        }
        run += __shfl(sc, 63);
    }
    if (t == 1023) rowptr[N_NODES] = run;
}

__global__ void scatter_kernel(const int* __restrict__ src, const int* __restrict__ dst,
                               int* __restrict__ cursor, int* __restrict__ col) {
    int i = blockIdx.x * blockDim.x + threadIdx.x;
    if (i < N_EDGES) {
        int d = dst[i];
        int pos = atomicAdd(&cursor[d], 1);
        col[pos] = src[i];
    } else if (i < N_EDGES + N_NODES) {
        int n = i - N_EDGES;
        int pos = atomicAdd(&cursor[n], 1);
        col[pos] = n;
    }
}

// ---------------------------------------------------------------------------
// Splitters -> swizzled k-tiled planes
// ---------------------------------------------------------------------------

__global__ void x_split_kernel(const float* __restrict__ x, _Float16* __restrict__ pl,
                               size_t pstride) {
    int i = blockIdx.x * blockDim.x + threadIdx.x;
    if (i >= N_NODES * 64) return;
    int n = i >> 6, k = i & 63;
    _Float16 a, b;
    split2(x[i], a, b);
    size_t off = (size_t)(k >> 5) * ((size_t)N_PAD * 32) + (size_t)n * 32 +
                 ((((k >> 3) & 3) ^ (n & 3)) << 3) + (k & 7);
    pl[off] = a;
    pl[pstride + off] = b;
}

struct W5 { const float* p[5]; };

// all 5 layers in one launch: t = l*65536 + c*256 + k
__global__ void w_split_kernel(W5 ws, _Float16* __restrict__ wt) {
    int t = blockIdx.x * blockDim.x + threadIdx.x;
    int l = t >> 16;
    int r = t & 65535;
    int c = r >> 8, k = r & 255;
    int K = (l == 0) ? 64 : 256;
    int NC = (l == 4) ? 40 : 256;
    float v = (k < K && c < NC) ? ws.p[l][k * NC + c] : 0.f;
    _Float16 a, b;
    split2(v, a, b);
    size_t off = (size_t)l * 131072 +
                 (size_t)(k >> 5) * 8192 + (size_t)c * 32 +
                 ((((k >> 3) & 3) ^ (c & 3)) << 3) + (k & 7);
    wt[off] = a;
    wt[65536 + off] = b;
}

// ---------------------------------------------------------------------------
// f16x2 MFMA GEMM, double-buffered global_load_lds staging (round-13 proven
// structure): wave w stages one 8KB plane-slab (w0->A.p0, w1->A.p1,
// w2->B.p0, w3->B.p1); one barrier per k-tile, next-tile loads issued
// before compute.
// FUSE_ATTN=1 (layers 0-3): C = f32 h [N][256] + fused asn/adn (CH=64).
// FUSE_ATTN=2 (layer 4):   C = f32 [N][40] guarded + fused 4-head masked
//                          asn/adn dot (n0==0; wc==0 waves hold all 40 cols).
// 3 MFMAs per (i,j): a0b0 + a0b1 + a1b0  (a1b1 ~ 2^-22, dropped).
// ---------------------------------------------------------------------------

template <int FUSE_ATTN>
__global__ __launch_bounds__(256) void gemm_mfma_kernel(
        const _Float16* __restrict__ Apl, size_t apstride,
        const _Float16* __restrict__ Wt,   // swizzled k-tiled [2][kt][256][32]
        float* __restrict__ C, int K, int NC,
        const float* __restrict__ as_flat, const float* __restrict__ ad_flat,
        float* __restrict__ asn, float* __restrict__ adn) {
    __shared__ __align__(16) _Float16 lds[2][16384];   // 2 x 32KB

    const int tid = threadIdx.x;
    const int lane = tid & 63;
    const int wave = tid >> 6;
    const int wr = (wave >> 1) * 64;
    const int wc = (wave & 1) * 64;
    const int m0 = blockIdx.x * 128;
    const int n0 = blockIdx.y * 128;
    const bool wave_active = (FUSE_ATTN == 1) || ((n0 + wc) < NC);

    f32x4 acc[4][4];
#pragma unroll
    for (int i = 0; i < 4; ++i)
#pragma unroll
        for (int j = 0; j < 4; ++j) acc[i][j] = (f32x4){0.f, 0.f, 0.f, 0.f};

    // staging sources for this wave's plane-slab
    const _Float16* gptr[8];
    size_t ktstep;
    {
        const _Float16* sbase;
        int rowbase;
        if (wave < 2) {
            sbase = Apl + (size_t)wave * apstride;
            rowbase = m0;
            ktstep = (size_t)N_PAD * 32;
        } else {
            sbase = Wt + (size_t)(wave - 2) * 65536;
            rowbase = n0;
            ktstep = 8192;
        }
#pragma unroll
        for (int it = 0; it < 8; ++it) {
            int idx = it * 64 + lane;
            gptr[it] = sbase + (size_t)(rowbase + (idx >> 2)) * 32 + (idx & 3) * 8;
        }
    }

    const int cswz = ((lane >> 4) ^ (lane & 3)) << 3;   // elems
    const int KT = K >> 5;

    // prologue: stage tile 0 into buf 0
#pragma unroll
    for (int it = 0; it < 8; ++it) {
        __builtin_amdgcn_global_load_lds(
            (const __attribute__((address_space(1))) void*)gptr[it],
            (__attribute__((address_space(3))) void*)((char*)&lds[0][0] + wave * 8192 + it * 1024),
            16, 0, 0);
    }

    for (int kt = 0; kt < KT; ++kt) {
        __syncthreads();   // drains my in-flight loads (buf[kt&1] ready) and
                           // guarantees all waves done reading buf[(kt+1)&1]

        if (kt + 1 < KT) {
            char* dstw = (char*)&lds[(kt + 1) & 1][0] + wave * 8192;
#pragma unroll
            for (int it = 0; it < 8; ++it) {
                __builtin_amdgcn_global_load_lds(
                    (const __attribute__((address_space(1))) void*)(gptr[it] + (size_t)(kt + 1) * ktstep),
                    (__attribute__((address_space(3))) void*)(dstw + it * 1024),
                    16, 0, 0);
            }
        }

        if (wave_active) {
            const _Float16* Ab = &lds[kt & 1][0];
            const _Float16* Bb = Ab + 8192;

            half8_t bf[2][4];
#pragma unroll
            for (int p = 0; p < 2; ++p)
#pragma unroll
                for (int j = 0; j < 4; ++j) {
                    int r = wc + j * 16 + (lane & 15);
                    bf[p][j] = *(const half8_t*)(Bb + p * 4096 + r * 32 + cswz);
                }
#pragma unroll
            for (int i = 0; i < 4; ++i) {
                int r = wr + i * 16 + (lane & 15);
                half8_t af0 = *(const half8_t*)(Ab + r * 32 + cswz);
                half8_t af1 = *(const half8_t*)(Ab + 4096 + r * 32 + cswz);
#pragma unroll
                for (int j = 0; j < 4; ++j) {
                    f32x4 c = acc[i][j];
                    c = __builtin_amdgcn_mfma_f32_16x16x32_f16(af0, bf[1][j], c, 0, 0, 0);
                    c = __builtin_amdgcn_mfma_f32_16x16x32_f16(af1, bf[0][j], c, 0, 0, 0);
                    c = __builtin_amdgcn_mfma_f32_16x16x32_f16(af0, bf[0][j], c, 0, 0, 0);
                    acc[i][j] = c;
                }
            }
        }
    }

    // epilogue: C/D mapping col = lane&15, row = (lane>>4)*4 + reg
    const int rbase = m0 + wr + (lane >> 4) * 4;
    const int cbase = n0 + wc + (lane & 15);

    if (FUSE_ATTN == 1) {
        // h -> f32 [N][256]
#pragma unroll
        for (int i = 0; i < 4; ++i)
#pragma unroll
            for (int j = 0; j < 4; ++j) {
                int gcol = cbase + j * 16;
#pragma unroll
                for (int r4 = 0; r4 < 4; ++r4) {
                    int grow = rbase + i * 16 + r4;
                    if (grow < N_NODES) C[(size_t)grow * 256 + gcol] = acc[i][j][r4];
                }
            }
        // fused asn/adn: this wave's 64 cols == head (n0+wc)>>6 (CH=64)
        const int hd_out = (n0 + wc) >> 6;
        float as_v[4], ad_v[4];
#pragma unroll
        for (int j = 0; j < 4; ++j) {
            int gc = cbase + j * 16;
            as_v[j] = as_flat[gc];
            ad_v[j] = ad_flat[gc];
        }
#pragma unroll
        for (int i = 0; i < 4; ++i)
#pragma unroll
            for (int r4 = 0; r4 < 4; ++r4) {
                float ps = 0.f, pd = 0.f;
#pragma unroll
                for (int j = 0; j < 4; ++j) {
                    float v = acc[i][j][r4];
                    ps += v * as_v[j];
                    pd += v * ad_v[j];
                }
#pragma unroll
                for (int o = 1; o < 16; o <<= 1) {
                    ps += __shfl_xor(ps, o);
                    pd += __shfl_xor(pd, o);
                }
                if ((lane & 15) == 0) {
                    int grow = rbase + i * 16 + r4;
                    if (grow < N_NODES) {
                        asn[grow * 4 + hd_out] = ps;
                        adn[grow * 4 + hd_out] = pd;
                    }
                }
            }
    } else {
        // C write, guarded (NC == 40, n0 == 0)
#pragma unroll
        for (int i = 0; i < 4; ++i)
#pragma unroll
            for (int j = 0; j < 4; ++j) {
                int gcol = cbase + j * 16;
                if (gcol >= NC) continue;
#pragma unroll
                for (int r4 = 0; r4 < 4; ++r4) {
                    int grow = rbase + i * 16 + r4;
                    if (grow < N_NODES) C[(size_t)grow * NC + gcol] = acc[i][j][r4];
                }
            }
        // fused 4-head masked attn dot: wc==0 waves hold cols 0..63 >= all 40
        if (wc == 0) {
            float as_v[4], ad_v[4];
            int hdj[4];
            bool valj[4];
#pragma unroll
            for (int j = 0; j < 4; ++j) {
                int gc = cbase + j * 16;
                valj[j] = gc < 40;
                as_v[j] = valj[j] ? as_flat[gc] : 0.f;
                ad_v[j] = valj[j] ? ad_flat[gc] : 0.f;
                hdj[j] = valj[j] ? (gc / 10) : -1;
            }
#pragma unroll
            for (int i = 0; i < 4; ++i)
#pragma unroll
                for (int r4 = 0; r4 < 4; ++r4) {
                    float p0 = 0.f, p1 = 0.f, p2 = 0.f, p3 = 0.f;
                    float q0 = 0.f, q1 = 0.f, q2 = 0.f, q3 = 0.f;
#pragma unroll
                    for (int j = 0; j < 4; ++j) {
                        float v = acc[i][j][r4];
                        float vs = v * as_v[j];
                        float vd = v * ad_v[j];
                        p0 += (hdj[j] == 0) ? vs : 0.f;
                        p1 += (hdj[j] == 1) ? vs : 0.f;
                        p2 += (hdj[j] == 2) ? vs : 0.f;
                        p3 += (hdj[j] == 3) ? vs : 0.f;
                        q0 += (hdj[j] == 0) ? vd : 0.f;
                        q1 += (hdj[j] == 1) ? vd : 0.f;
                        q2 += (hdj[j] == 2) ? vd : 0.f;
                        q3 += (hdj[j] == 3) ? vd : 0.f;
                    }
#pragma unroll
                    for (int o = 1; o < 16; o <<= 1) {
                        p0 += __shfl_xor(p0, o); p1 += __shfl_xor(p1, o);
                        p2 += __shfl_xor(p2, o); p3 += __shfl_xor(p3, o);
                        q0 += __shfl_xor(q0, o); q1 += __shfl_xor(q1, o);
                        q2 += __shfl_xor(q2, o); q3 += __shfl_xor(q3, o);
                    }
                    if ((lane & 15) == 0) {
                        int grow = rbase + i * 16 + r4;
                        if (grow < N_NODES) {
                            asn[grow * 4 + 0] = p0; asn[grow * 4 + 1] = p1;
                            asn[grow * 4 + 2] = p2; asn[grow * 4 + 3] = p3;
                            adn[grow * 4 + 0] = q0; adn[grow * 4 + 1] = q1;
                            adn[grow * 4 + 2] = q2; adn[grow * 4 + 3] = q3;
                        }
                    }
                }
        }
    }
}

// ---------------------------------------------------------------------------
// One-wave-per-node aggregation (CH=64 layers): lane = 4-channel block of the
// 256-col row; one float4 per lane per edge (1KB coalesced wave-read, f32 h).
// Per-head softmax in 16-lane groups; p/src broadcast via shfl.
// Emits the next GEMM's A in swizzled k-tiled f16x2 layout.
// ---------------------------------------------------------------------------

__global__ __launch_bounds__(256) void aggregate64_kernel(
        const float* __restrict__ h,   // [N][256] f32
        const float* __restrict__ asn, const float* __restrict__ adn,
        const int* __restrict__ rowptr, const int* __restrict__ col,
        const float* __restrict__ bias,
        _Float16* __restrict__ pl, size_t pstride) {
    const int n = (blockIdx.x << 2) + (threadIdx.x >> 6);
    const int lane = threadIdx.x & 63;
    const int hd = lane >> 4;
    const int e16 = lane & 15;
    const int pbase = lane & 48;

    const int start = rowptr[n];
    const int end = rowptr[n + 1];
    const float adv = adn[(n << 2) | hd];

    float m = -INFINITY, s = 0.f;
    float a0 = 0.f, a1 = 0.f, a2 = 0.f, a3 = 0.f;

    for (int e0 = start; e0 < end; e0 += 16) {
        int e = e0 + e16;
        int srcl = n;
        float ev = -INFINITY;
        if (e < end) {
            srcl = col[e];
            float t = asn[(srcl << 2) | hd] + adv;
            ev = (t > 0.f) ? t : 0.2f * t;   // leaky_relu(0.2)
        }
        float bm = ev;
#pragma unroll
        for (int o = 1; o < 16; o <<= 1) bm = fmaxf(bm, __shfl_xor(bm, o));
        float mn = fmaxf(m, bm);
        float scale = __expf(m - mn);
        float p = __expf(ev - mn);
        float ps = p;
#pragma unroll
        for (int o = 1; o < 16; o <<= 1) ps += __shfl_xor(ps, o);
        s = s * scale + ps;
        a0 *= scale; a1 *= scale; a2 *= scale; a3 *= scale;
        m = mn;

        int cnt = end - e0; if (cnt > 16) cnt = 16;
        int cnt4 = (cnt + 3) & ~3;
        for (int j0 = 0; j0 < cnt4; j0 += 4) {
            int sj[4]; float pj[4];
#pragma unroll
            for (int j = 0; j < 4; ++j) {
                sj[j] = __shfl(srcl, j0 + j);
                pj[j] = __shfl(p, pbase + j0 + j);
            }
            float4 hv[4];
#pragma unroll
            for (int j = 0; j < 4; ++j)
                hv[j] = *reinterpret_cast<const float4*>(h + (size_t)sj[j] * 256 + (lane << 2));
#pragma unroll
            for (int j = 0; j < 4; ++j) {
                a0 += pj[j] * hv[j].x;
                a1 += pj[j] * hv[j].y;
                a2 += pj[j] * hv[j].z;
                a3 += pj[j] * hv[j].w;
            }
        }
    }

    float sd = s + 1e-16f;
    const float* bp = bias + (lane << 2);
    float v0 = fmaxf(a0 / sd + bp[0], 0.f);
    float v1 = fmaxf(a1 / sd + bp[1], 0.f);
    float v2 = fmaxf(a2 / sd + bp[2], 0.f);
    float v3 = fmaxf(a3 / sd + bp[3], 0.f);

    _Float16 s0a, s0b, s1a, s1b, s2a, s2b, s3a, s3b;
    split2(v0, s0a, s0b);
    split2(v1, s1a, s1b);
    split2(v2, s2a, s2b);
    split2(v3, s3a, s3b);
    half4_t o0, o1;
    o0[0] = s0a; o0[1] = s1a; o0[2] = s2a; o0[3] = s3a;
    o1[0] = s0b; o1[1] = s1b; o1[2] = s2b; o1[3] = s3b;

    // swizzled k-tiled emit: k = lane*4..+3
    const int kt = lane >> 3;
    const int cp = ((lane >> 1) & 3) ^ (n & 3);
    const int inner = (lane & 1) << 2;
    size_t off = (size_t)kt * ((size_t)N_PAD * 32) + (size_t)n * 32 + (cp << 3) + inner;
    *(half4_t*)(pl + off) = o0;
    *(half4_t*)(pl + pstride + off) = o1;
}

// ---------------------------------------------------------------------------
// Layer-4 aggregation (CH=10): one wave per node. Lanes 0..39 gather the
// whole 160B h-row per edge; softmax per head in 16-lane groups; p routed
// to channel lanes via shfl. Writes d_out.
// ---------------------------------------------------------------------------

__global__ __launch_bounds__(256) void aggregate_out10_kernel(
        const float* __restrict__ h,   // [N][40] f32
        const float* __restrict__ asn, const float* __restrict__ adn,
        const int* __restrict__ rowptr, const int* __restrict__ col,
        const float* __restrict__ bias, float* __restrict__ out) {
    const int n = (blockIdx.x << 2) + (threadIdx.x >> 6);
    const int lane = threadIdx.x & 63;
    const int hd16 = lane >> 4;          // softmax-role head
    const int e16 = lane & 15;
    const bool cvalid = lane < 40;
    const int hc = ((cvalid ? lane : 0) * 205) >> 11;   // lane/10: channel head

    const int start = rowptr[n];
    const int end = rowptr[n + 1];
    const float adv = adn[(n << 2) | hd16];

    float m = -INFINITY, s = 0.f, a0 = 0.f, a1 = 0.f;

    for (int e0 = start; e0 < end; e0 += 16) {
        int e = e0 + e16;
        int srcl = n;
        float ev = -INFINITY;
        if (e < end) {
            srcl = col[e];
            float t = asn[(srcl << 2) | hd16] + adv;
            ev = (t > 0.f) ? t : 0.2f * t;
        }
        float bm = ev;
#pragma unroll
        for (int o = 1; o < 16; o <<= 1) bm = fmaxf(bm, __shfl_xor(bm, o));
        float mn = fmaxf(m, bm);
        float scale = __expf(m - mn);
        float p = __expf(ev - mn);
        float ps = p;
#pragma unroll
        for (int o = 1; o < 16; o <<= 1) ps += __shfl_xor(ps, o);
        s = s * scale + ps;
        m = mn;

        float sc_c = __shfl(scale, hc * 16);   // my channel-head's scale
        a0 *= sc_c;
        a1 *= sc_c;

        int cnt = end - e0; if (cnt > 16) cnt = 16;
        int cnt4 = (cnt + 3) & ~3;
        for (int j0 = 0; j0 < cnt4; j0 += 4) {
            int sj[4]; float pj[4];
#pragma unroll
            for (int j = 0; j < 4; ++j) {
                sj[j] = __shfl(srcl, j0 + j);
                pj[j] = __shfl(p, hc * 16 + j0 + j);
            }
            float hv[4];
#pragma unroll
            for (int j = 0; j < 4; ++j)
                hv[j] = cvalid ? h[(size_t)sj[j] * 40 + lane] : 0.f;
            a0 += pj[0] * hv[0];
            a1 += pj[1] * hv[1];
            a0 += pj[2] * hv[2];
            a1 += pj[3] * hv[3];
        }
    }

    float sd = __shfl(s, hc * 16) + 1e-16f;
    if (cvalid) {
        float v = (a0 + a1) / sd + bias[lane];
        out[(size_t)n * 40 + lane] = fmaxf(v, 0.f);
    }
}

// ---------------------------------------------------------------------------

extern "C" void kernel_launch(void* const* d_in, const int* in_sizes, int n_in,
                              void* d_out, int out_size, void* d_ws, size_t ws_size,
                              hipStream_t stream) {
    const float* x_in = (const float*)d_in[0];
    const int* ei = (const int*)d_in[1];
    const int* src = ei;
    const int* dst = ei + N_EDGES;

    const float *AS[5], *AD[5], *BI[5];
    W5 w5;
    for (int l = 0; l < 5; ++l) {
        w5.p[l] = (const float*)d_in[2 + l * 4 + 0];
        AS[l] = (const float*)d_in[2 + l * 4 + 1];
        AD[l] = (const float*)d_in[2 + l * 4 + 2];
        BI[l] = (const float*)d_in[2 + l * 4 + 3];
    }

    // workspace carve-up
    const size_t PSTRIDE = (size_t)N_PAD * 256;           // elements per plane
    _Float16* planes = (_Float16*)d_ws;                   // GEMM A planes (2, swizzled k-tiled)
    float* hbuf = (float*)(planes + 2 * PSTRIDE);         // h f32 [N][256] (layer4: [N][40])
    float* asn  = hbuf + (size_t)N_NODES * 256;
    float* adn  = asn + (size_t)N_NODES * HEADS;
    int* rowptr = (int*)(adn + (size_t)N_NODES * HEADS);  // N+1
    int* cursor = rowptr + (N_NODES + 1);
    int* col    = cursor + N_NODES;                       // E + N
    _Float16* wt = (_Float16*)(((uintptr_t)(col + N_EDGES + N_NODES) + 15) & ~(uintptr_t)15);

    // --- CSR build ---
    init_deg_kernel<<<(N_NODES + 255) / 256, 256, 0, stream>>>(cursor);
    hist_kernel<<<(N_EDGES + 255) / 256, 256, 0, stream>>>(dst, cursor);
    scan_kernel<<<1, 1024, 0, stream>>>(cursor, rowptr, cursor);
    scatter_kernel<<<(N_EDGES + N_NODES + 255) / 256, 256, 0, stream>>>(src, dst, cursor, col);

    // --- weight & input splits (swizzled k-tiled) ---
    w_split_kernel<<<5 * 65536 / 256, 256, 0, stream>>>(w5, wt);
    x_split_kernel<<<(N_NODES * 64 + 255) / 256, 256, 0, stream>>>(x_in, planes, PSTRIDE);

    // --- 5 GAT layers ---
    for (int l = 0; l < 5; ++l) {
        const int K = (l == 0) ? 64 : 256;
        const int NC = (l == 4) ? 40 : 256;
        dim3 ggrid(N_PAD / 128, (NC + 127) / 128);
        const _Float16* wl = wt + (size_t)l * 131072;
        if (l < 4) {
            gemm_mfma_kernel<1><<<ggrid, 256, 0, stream>>>(
                planes, PSTRIDE, wl, hbuf, K, NC, AS[l], AD[l], asn, adn);
            aggregate64_kernel<<<N_NODES / 4, 256, 0, stream>>>(
                hbuf, asn, adn, rowptr, col, BI[l], planes, PSTRIDE);
        } else {
            gemm_mfma_kernel<2><<<ggrid, 256, 0, stream>>>(
                planes, PSTRIDE, wl, hbuf, K, NC, AS[l], AD[l], asn, adn);
            aggregate_out10_kernel<<<N_NODES / 4, 256, 0, stream>>>(
                hbuf, asn, adn, rowptr, col, BI[l], (float*)d_out);
        }
    }
    (void)in_sizes; (void)n_in; (void)out_size; (void)ws_size;
}

// Round 16
// 823.935 us; speedup vs baseline: 1.0322x; 1.0282x over previous
//
#include <hip/hip_runtime.h>
#include <hip/hip_bf16.h>
#include <math.h>

#define N_NODES 50000
#define N_PAD   50048   // 391 * 128
#define N_EDGES 800000
#define HEADS 4

typedef __attribute__((ext_vector_type(8))) _Float16 half8_t;
typedef __attribute__((ext_vector_type(4))) _Float16 half4_t;
typedef __attribute__((ext_vector_type(4))) float f32x4;

// 2-way f16 split: v ~= (float)p0 + (float)p1, exact to ~2^-23 relative.
__device__ inline void split2(float v, _Float16& p0, _Float16& p1) {
    p0 = (_Float16)v;
    p1 = (_Float16)(v - (float)p0);
}

// Swizzled k-tiled plane layout (A and W planes, staged via global_load_lds):
//   elem (row, k) at  (k>>5)*rows*32 + row*32 + ((((k>>3)&3) ^ (row&3))<<3) + (k&7)
__device__ inline size_t ktiled_off(int row, int k, size_t rowcap) {
    return (size_t)(k >> 5) * (rowcap * 32) + (size_t)row * 32 +
           ((((k >> 3) & 3) ^ (row & 3)) << 3) + (k & 7);
}

// ---------------------------------------------------------------------------
// CSR construction
// ---------------------------------------------------------------------------

__global__ void init_deg_kernel(int* __restrict__ deg) {
    int i = blockIdx.x * blockDim.x + threadIdx.x;
    if (i < N_NODES) deg[i] = 1;  // self-loop
}

__global__ void hist_kernel(const int* __restrict__ dst, int* __restrict__ deg) {
    int i = blockIdx.x * blockDim.x + threadIdx.x;
    if (i < N_EDGES) atomicAdd(&deg[dst[i]], 1);
}

// Wave-coalesced two-phase scan (16 waves, contiguous chunks).
__global__ __launch_bounds__(1024) void scan_kernel(const int* __restrict__ deg,
                                                    int* __restrict__ rowptr,
                                                    int* __restrict__ cursor) {
    __shared__ int wsums[16];
    const int t = threadIdx.x;
    const int wv = t >> 6, ln = t & 63;
    const int WCHUNK = (N_NODES + 15) / 16;   // 3125
    const int base = wv * WCHUNK;
    int lim = base + WCHUNK; if (lim > N_NODES) lim = N_NODES;

    int tot = 0;
    for (int i = base + ln; i < lim; i += 64) tot += deg[i];
#pragma unroll
    for (int o = 1; o < 64; o <<= 1) tot += __shfl_xor(tot, o);
    if (ln == 0) wsums[wv] = tot;
    __syncthreads();

    int run = 0;
    for (int w = 0; w < wv; ++w) run += wsums[w];

    for (int i0 = base; i0 < lim; i0 += 64) {
        int i = i0 + ln;
        int d = (i < lim) ? deg[i] : 0;
        int sc = d;
#pragma unroll
        for (int o = 1; o < 64; o <<= 1) {
            int v = __shfl_up(sc, o);
            if (ln >= o) sc += v;
        }
        if (i < lim) {
            int val = run + sc - d;
            rowptr[i] = val;
            cursor[i] = val;
        }
        run += __shfl(sc, 63);
    }
    if (t == 1023) rowptr[N_NODES] = run;
}

__global__ void scatter_kernel(const int* __restrict__ src, const int* __restrict__ dst,
                               int* __restrict__ cursor, int* __restrict__ col) {
    int i = blockIdx.x * blockDim.x + threadIdx.x;
    if (i < N_EDGES) {
        int d = dst[i];
        int pos = atomicAdd(&cursor[d], 1);
        col[pos] = src[i];
    } else if (i < N_EDGES + N_NODES) {
        int n = i - N_EDGES;
        int pos = atomicAdd(&cursor[n], 1);
        col[pos] = n;
    }
}

// ---------------------------------------------------------------------------
// Weight splitter -> swizzled k-tiled planes.
// Layer 0 is stored BLOCK-DIAGONAL 256x256: A-col index = hd*64 + k'
// (per-head aggregated input), out col c = hd*64+c' uses W0[k'][c] iff the
// head blocks match.
// ---------------------------------------------------------------------------

struct W5 { const float* p[5]; };

__global__ void w_split_kernel(W5 ws, _Float16* __restrict__ wt) {
    int t = blockIdx.x * blockDim.x + threadIdx.x;
    int l = t >> 16;
    int r = t & 65535;
    int c = r >> 8, k = r & 255;
    float v;
    if (l == 0) {
        v = ((k >> 6) == (c >> 6)) ? ws.p[0][(k & 63) * 256 + c] : 0.f;
    } else {
        int K = 256;
        int NC = (l == 4) ? 40 : 256;
        v = (k < K && c < NC) ? ws.p[l][k * NC + c] : 0.f;
    }
    _Float16 a, b;
    split2(v, a, b);
    size_t off = (size_t)l * 131072 + ktiled_off(c, k, 256);
    wt[off] = a;
    wt[65536 + off] = b;
}

// avec0[hd][k] = sum_c W0[k][hd*64+c] * as0[hd*64+c]  (and dvec0 with ad0)
__global__ void avec0_kernel(const float* __restrict__ W0,
                             const float* __restrict__ as0, const float* __restrict__ ad0,
                             float* __restrict__ avec, float* __restrict__ dvec) {
    int t = threadIdx.x;           // 256 threads: hd = t>>6, k = t&63
    int hd = t >> 6, k = t & 63;
    float s1 = 0.f, s2 = 0.f;
    for (int c = 0; c < 64; ++c) {
        float w = W0[k * 256 + hd * 64 + c];
        s1 += w * as0[hd * 64 + c];
        s2 += w * ad0[hd * 64 + c];
    }
    avec[t] = s1;
    dvec[t] = s2;
}

// asn0[n][hd] = <x0[n], avec0[hd]>  (64-dim dot)
__global__ void attn0_kernel(const float* __restrict__ x0,
                             const float* __restrict__ avec, const float* __restrict__ dvec,
                             float* __restrict__ asn, float* __restrict__ adn) {
    int t = blockIdx.x * blockDim.x + threadIdx.x;
    if (t >= N_NODES * HEADS) return;
    int n = t >> 2, hd = t & 3;
    const float* xp = x0 + (size_t)n * 64;
    const float* ap = avec + hd * 64;
    const float* dp = dvec + hd * 64;
    float s1 = 0.f, s2 = 0.f;
    for (int c = 0; c < 64; c += 4) {
        float4 xv = *reinterpret_cast<const float4*>(&xp[c]);
        float4 av = *reinterpret_cast<const float4*>(&ap[c]);
        float4 dv = *reinterpret_cast<const float4*>(&dp[c]);
        s1 += xv.x * av.x + xv.y * av.y + xv.z * av.z + xv.w * av.w;
        s2 += xv.x * dv.x + xv.y * dv.y + xv.z * dv.z + xv.w * dv.w;
    }
    asn[t] = s1;
    adn[t] = s2;
}

// ---------------------------------------------------------------------------
// Layer-0 aggregation over the 64-dim INPUT x0 (aggregation commutes with
// the GEMM). One wave per node; lane = channel k (0..63); per-head softmax
// in 16-lane groups; each lane accumulates y0[hd][k] for all 4 heads.
// Emits y0 as f16x2 k-tiled planes with col = hd*64 + k (block-diag W0').
// ---------------------------------------------------------------------------

__global__ __launch_bounds__(256) void aggregate_x0_kernel(
        const float* __restrict__ x0,   // [N][64] f32
        const float* __restrict__ asn, const float* __restrict__ adn,
        const int* __restrict__ rowptr, const int* __restrict__ col,
        _Float16* __restrict__ pl, size_t pstride) {
    const int n = (blockIdx.x << 2) + (threadIdx.x >> 6);
    const int lane = threadIdx.x & 63;
    const int hdg = lane >> 4;       // softmax-role head of this lane
    const int e16 = lane & 15;

    const int start = rowptr[n];
    const int end = rowptr[n + 1];
    const float adv = adn[(n << 2) | hdg];

    float m = -INFINITY, s = 0.f;
    float a0 = 0.f, a1 = 0.f, a2 = 0.f, a3 = 0.f;   // y0[hd][lane]

    for (int e0 = start; e0 < end; e0 += 16) {
        int e = e0 + e16;
        int srcl = n;
        float ev = -INFINITY;
        if (e < end) {
            srcl = col[e];
            float t = asn[(srcl << 2) | hdg] + adv;
            ev = (t > 0.f) ? t : 0.2f * t;   // leaky_relu(0.2)
        }
        float bm = ev;
#pragma unroll
        for (int o = 1; o < 16; o <<= 1) bm = fmaxf(bm, __shfl_xor(bm, o));
        float mn = fmaxf(m, bm);
        float scale = __expf(m - mn);
        float p = __expf(ev - mn);
        float ps = p;
#pragma unroll
        for (int o = 1; o < 16; o <<= 1) ps += __shfl_xor(ps, o);
        s = s * scale + ps;
        m = mn;

        // rescale accumulators by each head's scale (group-uniform)
        a0 *= __shfl(scale, 0);
        a1 *= __shfl(scale, 16);
        a2 *= __shfl(scale, 32);
        a3 *= __shfl(scale, 48);

        int cnt = end - e0; if (cnt > 16) cnt = 16;
        int cnt4 = (cnt + 3) & ~3;
        for (int j0 = 0; j0 < cnt4; j0 += 4) {
#pragma unroll
            for (int j = 0; j < 4; ++j) {
                int sj = __shfl(srcl, j0 + j);
                float xv = x0[(size_t)sj * 64 + lane];
                a0 += __shfl(p, j0 + j) * xv;
                a1 += __shfl(p, 16 + j0 + j) * xv;
                a2 += __shfl(p, 32 + j0 + j) * xv;
                a3 += __shfl(p, 48 + j0 + j) * xv;
            }
        }
    }

    float v0 = a0 / (__shfl(s, 0) + 1e-16f);
    float v1 = a1 / (__shfl(s, 16) + 1e-16f);
    float v2 = a2 / (__shfl(s, 32) + 1e-16f);
    float v3 = a3 / (__shfl(s, 48) + 1e-16f);

    // emit 4 values at cols hd*64 + lane (k-tiled, 2 planes)
    float vv[1];
    _Float16 pa, pb;
#define EMIT_Y0(V, HD)                                        \
    {                                                          \
        split2((V), pa, pb);                                   \
        size_t off = ktiled_off(n, (HD) * 64 + lane, N_PAD);   \
        pl[off] = pa;                                          \
        pl[pstride + off] = pb;                                \
    }
    EMIT_Y0(v0, 0) EMIT_Y0(v1, 1) EMIT_Y0(v2, 2) EMIT_Y0(v3, 3)
#undef EMIT_Y0
    (void)vv;
}

// ---------------------------------------------------------------------------
// f16x2 MFMA GEMM, double-buffered global_load_lds staging (round-13 proven
// structure): wave w stages one 8KB plane-slab; one barrier per k-tile,
// next-tile loads issued before compute.
// FUSE_ATTN=1 (layers 1-3): C = f32 h [N][256] + fused asn/adn (CH=64).
// FUSE_ATTN=2 (layer 4):   C = f32 [N][40] guarded + fused 4-head masked dot.
// FUSE_ATTN=3 (layer 0):   x1 = relu(acc + bias) -> f16x2 k-tiled planes.
// 3 MFMAs per (i,j): a0b0 + a0b1 + a1b0  (a1b1 ~ 2^-22, dropped).
// ---------------------------------------------------------------------------

template <int FUSE_ATTN>
__global__ __launch_bounds__(256) void gemm_mfma_kernel(
        const _Float16* __restrict__ Apl, size_t apstride,
        const _Float16* __restrict__ Wt,   // swizzled k-tiled [2][kt][256][32]
        float* __restrict__ C, int K, int NC,
        const float* __restrict__ as_flat, const float* __restrict__ ad_flat,
        float* __restrict__ asn, float* __restrict__ adn,
        const float* __restrict__ bias, _Float16* __restrict__ opl, size_t opstride) {
    __shared__ __align__(16) _Float16 lds[2][16384];   // 2 x 32KB

    const int tid = threadIdx.x;
    const int lane = tid & 63;
    const int wave = tid >> 6;
    const int wr = (wave >> 1) * 64;
    const int wc = (wave & 1) * 64;
    const int m0 = blockIdx.x * 128;
    const int n0 = blockIdx.y * 128;
    const bool wave_active = (FUSE_ATTN != 2) || ((n0 + wc) < NC);

    f32x4 acc[4][4];
#pragma unroll
    for (int i = 0; i < 4; ++i)
#pragma unroll
        for (int j = 0; j < 4; ++j) acc[i][j] = (f32x4){0.f, 0.f, 0.f, 0.f};

    // staging sources for this wave's plane-slab
    const _Float16* gptr[8];
    size_t ktstep;
    {
        const _Float16* sbase;
        int rowbase;
        if (wave < 2) {
            sbase = Apl + (size_t)wave * apstride;
            rowbase = m0;
            ktstep = (size_t)N_PAD * 32;
        } else {
            sbase = Wt + (size_t)(wave - 2) * 65536;
            rowbase = n0;
            ktstep = 8192;
        }
#pragma unroll
        for (int it = 0; it < 8; ++it) {
            int idx = it * 64 + lane;
            gptr[it] = sbase + (size_t)(rowbase + (idx >> 2)) * 32 + (idx & 3) * 8;
        }
    }

    const int cswz = ((lane >> 4) ^ (lane & 3)) << 3;   // elems
    const int KT = K >> 5;

    // prologue: stage tile 0 into buf 0
#pragma unroll
    for (int it = 0; it < 8; ++it) {
        __builtin_amdgcn_global_load_lds(
            (const __attribute__((address_space(1))) void*)gptr[it],
            (__attribute__((address_space(3))) void*)((char*)&lds[0][0] + wave * 8192 + it * 1024),
            16, 0, 0);
    }

    for (int kt = 0; kt < KT; ++kt) {
        __syncthreads();

        if (kt + 1 < KT) {
            char* dstw = (char*)&lds[(kt + 1) & 1][0] + wave * 8192;
#pragma unroll
            for (int it = 0; it < 8; ++it) {
                __builtin_amdgcn_global_load_lds(
                    (const __attribute__((address_space(1))) void*)(gptr[it] + (size_t)(kt + 1) * ktstep),
                    (__attribute__((address_space(3))) void*)(dstw + it * 1024),
                    16, 0, 0);
            }
        }

        if (wave_active) {
            const _Float16* Ab = &lds[kt & 1][0];
            const _Float16* Bb = Ab + 8192;

            half8_t bf[2][4];
#pragma unroll
            for (int p = 0; p < 2; ++p)
#pragma unroll
                for (int j = 0; j < 4; ++j) {
                    int r = wc + j * 16 + (lane & 15);
                    bf[p][j] = *(const half8_t*)(Bb + p * 4096 + r * 32 + cswz);
                }
#pragma unroll
            for (int i = 0; i < 4; ++i) {
                int r = wr + i * 16 + (lane & 15);
                half8_t af0 = *(const half8_t*)(Ab + r * 32 + cswz);
                half8_t af1 = *(const half8_t*)(Ab + 4096 + r * 32 + cswz);
#pragma unroll
                for (int j = 0; j < 4; ++j) {
                    f32x4 c = acc[i][j];
                    c = __builtin_amdgcn_mfma_f32_16x16x32_f16(af0, bf[1][j], c, 0, 0, 0);
                    c = __builtin_amdgcn_mfma_f32_16x16x32_f16(af1, bf[0][j], c, 0, 0, 0);
                    c = __builtin_amdgcn_mfma_f32_16x16x32_f16(af0, bf[0][j], c, 0, 0, 0);
                    acc[i][j] = c;
                }
            }
        }
    }

    // epilogue: C/D mapping col = lane&15, row = (lane>>4)*4 + reg
    const int rbase = m0 + wr + (lane >> 4) * 4;
    const int cbase = n0 + wc + (lane & 15);

    if (FUSE_ATTN == 1) {
        // h -> f32 [N][256]
#pragma unroll
        for (int i = 0; i < 4; ++i)
#pragma unroll
            for (int j = 0; j < 4; ++j) {
                int gcol = cbase + j * 16;
#pragma unroll
                for (int r4 = 0; r4 < 4; ++r4) {
                    int grow = rbase + i * 16 + r4;
                    if (grow < N_NODES) C[(size_t)grow * 256 + gcol] = acc[i][j][r4];
                }
            }
        const int hd_out = (n0 + wc) >> 6;
        float as_v[4], ad_v[4];
#pragma unroll
        for (int j = 0; j < 4; ++j) {
            int gc = cbase + j * 16;
            as_v[j] = as_flat[gc];
            ad_v[j] = ad_flat[gc];
        }
#pragma unroll
        for (int i = 0; i < 4; ++i)
#pragma unroll
            for (int r4 = 0; r4 < 4; ++r4) {
                float ps = 0.f, pd = 0.f;
#pragma unroll
                for (int j = 0; j < 4; ++j) {
                    float v = acc[i][j][r4];
                    ps += v * as_v[j];
                    pd += v * ad_v[j];
                }
#pragma unroll
                for (int o = 1; o < 16; o <<= 1) {
                    ps += __shfl_xor(ps, o);
                    pd += __shfl_xor(pd, o);
                }
                if ((lane & 15) == 0) {
                    int grow = rbase + i * 16 + r4;
                    if (grow < N_NODES) {
                        asn[grow * 4 + hd_out] = ps;
                        adn[grow * 4 + hd_out] = pd;
                    }
                }
            }
    } else if (FUSE_ATTN == 2) {
#pragma unroll
        for (int i = 0; i < 4; ++i)
#pragma unroll
            for (int j = 0; j < 4; ++j) {
                int gcol = cbase + j * 16;
                if (gcol >= NC) continue;
#pragma unroll
                for (int r4 = 0; r4 < 4; ++r4) {
                    int grow = rbase + i * 16 + r4;
                    if (grow < N_NODES) C[(size_t)grow * NC + gcol] = acc[i][j][r4];
                }
            }
        if (wc == 0) {
            float as_v[4], ad_v[4];
            int hdj[4];
#pragma unroll
            for (int j = 0; j < 4; ++j) {
                int gc = cbase + j * 16;
                bool valj = gc < 40;
                as_v[j] = valj ? as_flat[gc] : 0.f;
                ad_v[j] = valj ? ad_flat[gc] : 0.f;
                hdj[j] = valj ? (gc / 10) : -1;
            }
#pragma unroll
            for (int i = 0; i < 4; ++i)
#pragma unroll
                for (int r4 = 0; r4 < 4; ++r4) {
                    float p0 = 0.f, p1 = 0.f, p2 = 0.f, p3 = 0.f;
                    float q0 = 0.f, q1 = 0.f, q2 = 0.f, q3 = 0.f;
#pragma unroll
                    for (int j = 0; j < 4; ++j) {
                        float v = acc[i][j][r4];
                        float vs = v * as_v[j];
                        float vd = v * ad_v[j];
                        p0 += (hdj[j] == 0) ? vs : 0.f;
                        p1 += (hdj[j] == 1) ? vs : 0.f;
                        p2 += (hdj[j] == 2) ? vs : 0.f;
                        p3 += (hdj[j] == 3) ? vs : 0.f;
                        q0 += (hdj[j] == 0) ? vd : 0.f;
                        q1 += (hdj[j] == 1) ? vd : 0.f;
                        q2 += (hdj[j] == 2) ? vd : 0.f;
                        q3 += (hdj[j] == 3) ? vd : 0.f;
                    }
#pragma unroll
                    for (int o = 1; o < 16; o <<= 1) {
                        p0 += __shfl_xor(p0, o); p1 += __shfl_xor(p1, o);
                        p2 += __shfl_xor(p2, o); p3 += __shfl_xor(p3, o);
                        q0 += __shfl_xor(q0, o); q1 += __shfl_xor(q1, o);
                        q2 += __shfl_xor(q2, o); q3 += __shfl_xor(q3, o);
                    }
                    if ((lane & 15) == 0) {
                        int grow = rbase + i * 16 + r4;
                        if (grow < N_NODES) {
                            asn[grow * 4 + 0] = p0; asn[grow * 4 + 1] = p1;
                            asn[grow * 4 + 2] = p2; asn[grow * 4 + 3] = p3;
                            adn[grow * 4 + 0] = q0; adn[grow * 4 + 1] = q1;
                            adn[grow * 4 + 2] = q2; adn[grow * 4 + 3] = q3;
                        }
                    }
                }
        }
    } else {
        // FUSE_ATTN == 3 (layer 0): x1 = relu(acc + bias) -> k-tiled planes
#pragma unroll
        for (int i = 0; i < 4; ++i)
#pragma unroll
            for (int j = 0; j < 4; ++j) {
                int gcol = cbase + j * 16;
                float bv = bias[gcol];
#pragma unroll
                for (int r4 = 0; r4 < 4; ++r4) {
                    int grow = rbase + i * 16 + r4;
                    if (grow < N_NODES) {
                        float v = fmaxf(acc[i][j][r4] + bv, 0.f);
                        _Float16 pa, pb;
                        split2(v, pa, pb);
                        size_t off = ktiled_off(grow, gcol, N_PAD);
                        opl[off] = pa;
                        opl[opstride + off] = pb;
                    }
                }
            }
    }
}

// ---------------------------------------------------------------------------
// One-wave-per-node aggregation (layers 1-3): lane = 4-channel block of the
// 256-col h row; one float4 per lane per edge (1KB coalesced wave-read).
// Per-head softmax in 16-lane groups; p/src broadcast via shfl.
// Emits the next GEMM's A in swizzled k-tiled f16x2 layout (bias+relu here).
// ---------------------------------------------------------------------------

__global__ __launch_bounds__(256) void aggregate64_kernel(
        const float* __restrict__ h,   // [N][256] f32
        const float* __restrict__ asn, const float* __restrict__ adn,
        const int* __restrict__ rowptr, const int* __restrict__ col,
        const float* __restrict__ bias,
        _Float16* __restrict__ pl, size_t pstride) {
    const int n = (blockIdx.x << 2) + (threadIdx.x >> 6);
    const int lane = threadIdx.x & 63;
    const int hd = lane >> 4;
    const int e16 = lane & 15;
    const int pbase = lane & 48;

    const int start = rowptr[n];
    const int end = rowptr[n + 1];
    const float adv = adn[(n << 2) | hd];

    float m = -INFINITY, s = 0.f;
    float a0 = 0.f, a1 = 0.f, a2 = 0.f, a3 = 0.f;

    for (int e0 = start; e0 < end; e0 += 16) {
        int e = e0 + e16;
        int srcl = n;
        float ev = -INFINITY;
        if (e < end) {
            srcl = col[e];
            float t = asn[(srcl << 2) | hd] + adv;
            ev = (t > 0.f) ? t : 0.2f * t;   // leaky_relu(0.2)
        }
        float bm = ev;
#pragma unroll
        for (int o = 1; o < 16; o <<= 1) bm = fmaxf(bm, __shfl_xor(bm, o));
        float mn = fmaxf(m, bm);
        float scale = __expf(m - mn);
        float p = __expf(ev - mn);
        float ps = p;
#pragma unroll
        for (int o = 1; o < 16; o <<= 1) ps += __shfl_xor(ps, o);
        s = s * scale + ps;
        a0 *= scale; a1 *= scale; a2 *= scale; a3 *= scale;
        m = mn;

        int cnt = end - e0; if (cnt > 16) cnt = 16;
        int cnt4 = (cnt + 3) & ~3;
        for (int j0 = 0; j0 < cnt4; j0 += 4) {
            int sj[4]; float pj[4];
#pragma unroll
            for (int j = 0; j < 4; ++j) {
                sj[j] = __shfl(srcl, j0 + j);
                pj[j] = __shfl(p, pbase + j0 + j);
            }
            float4 hv[4];
#pragma unroll
            for (int j = 0; j < 4; ++j)
                hv[j] = *reinterpret_cast<const float4*>(h + (size_t)sj[j] * 256 + (lane << 2));
#pragma unroll
            for (int j = 0; j < 4; ++j) {
                a0 += pj[j] * hv[j].x;
                a1 += pj[j] * hv[j].y;
                a2 += pj[j] * hv[j].z;
                a3 += pj[j] * hv[j].w;
            }
        }
    }

    float sd = s + 1e-16f;
    const float* bp = bias + (lane << 2);
    float v0 = fmaxf(a0 / sd + bp[0], 0.f);
    float v1 = fmaxf(a1 / sd + bp[1], 0.f);
    float v2 = fmaxf(a2 / sd + bp[2], 0.f);
    float v3 = fmaxf(a3 / sd + bp[3], 0.f);

    _Float16 s0a, s0b, s1a, s1b, s2a, s2b, s3a, s3b;
    split2(v0, s0a, s0b);
    split2(v1, s1a, s1b);
    split2(v2, s2a, s2b);
    split2(v3, s3a, s3b);
    half4_t o0, o1;
    o0[0] = s0a; o0[1] = s1a; o0[2] = s2a; o0[3] = s3a;
    o1[0] = s0b; o1[1] = s1b; o1[2] = s2b; o1[3] = s3b;

    // swizzled k-tiled emit: k = lane*4..+3
    const int kt = lane >> 3;
    const int cp = ((lane >> 1) & 3) ^ (n & 3);
    const int inner = (lane & 1) << 2;
    size_t off = (size_t)kt * ((size_t)N_PAD * 32) + (size_t)n * 32 + (cp << 3) + inner;
    *(half4_t*)(pl + off) = o0;
    *(half4_t*)(pl + pstride + off) = o1;
}

// ---------------------------------------------------------------------------
// Layer-4 aggregation (CH=10): one wave per node; lanes 0..39 gather the
// 160B h-row per edge; softmax per head in 16-lane groups. Writes d_out.
// ---------------------------------------------------------------------------

__global__ __launch_bounds__(256) void aggregate_out10_kernel(
        const float* __restrict__ h,   // [N][40] f32
        const float* __restrict__ asn, const float* __restrict__ adn,
        const int* __restrict__ rowptr, const int* __restrict__ col,
        const float* __restrict__ bias, float* __restrict__ out) {
    const int n = (blockIdx.x << 2) + (threadIdx.x >> 6);
    const int lane = threadIdx.x & 63;
    const int hd16 = lane >> 4;
    const int e16 = lane & 15;
    const bool cvalid = lane < 40;
    const int hc = ((cvalid ? lane : 0) * 205) >> 11;   // lane/10

    const int start = rowptr[n];
    const int end = rowptr[n + 1];
    const float adv = adn[(n << 2) | hd16];

    float m = -INFINITY, s = 0.f, a0 = 0.f, a1 = 0.f;

    for (int e0 = start; e0 < end; e0 += 16) {
        int e = e0 + e16;
        int srcl = n;
        float ev = -INFINITY;
        if (e < end) {
            srcl = col[e];
            float t = asn[(srcl << 2) | hd16] + adv;
            ev = (t > 0.f) ? t : 0.2f * t;
        }
        float bm = ev;
#pragma unroll
        for (int o = 1; o < 16; o <<= 1) bm = fmaxf(bm, __shfl_xor(bm, o));
        float mn = fmaxf(m, bm);
        float scale = __expf(m - mn);
        float p = __expf(ev - mn);
        float ps = p;
#pragma unroll
        for (int o = 1; o < 16; o <<= 1) ps += __shfl_xor(ps, o);
        s = s * scale + ps;
        m = mn;

        float sc_c = __shfl(scale, hc * 16);
        a0 *= sc_c;
        a1 *= sc_c;

        int cnt = end - e0; if (cnt > 16) cnt = 16;
        int cnt4 = (cnt + 3) & ~3;
        for (int j0 = 0; j0 < cnt4; j0 += 4) {
            int sj[4]; float pj[4];
#pragma unroll
            for (int j = 0; j < 4; ++j) {
                sj[j] = __shfl(srcl, j0 + j);
                pj[j] = __shfl(p, hc * 16 + j0 + j);
            }
            float hv[4];
#pragma unroll
            for (int j = 0; j < 4; ++j)
                hv[j] = cvalid ? h[(size_t)sj[j] * 40 + lane] : 0.f;
            a0 += pj[0] * hv[0];
            a1 += pj[1] * hv[1];
            a0 += pj[2] * hv[2];
            a1 += pj[3] * hv[3];
        }
    }

    float sd = __shfl(s, hc * 16) + 1e-16f;
    if (cvalid) {
        float v = (a0 + a1) / sd + bias[lane];
        out[(size_t)n * 40 + lane] = fmaxf(v, 0.f);
    }
}

// ---------------------------------------------------------------------------

extern "C" void kernel_launch(void* const* d_in, const int* in_sizes, int n_in,
                              void* d_out, int out_size, void* d_ws, size_t ws_size,
                              hipStream_t stream) {
    const float* x_in = (const float*)d_in[0];
    const int* ei = (const int*)d_in[1];
    const int* src = ei;
    const int* dst = ei + N_EDGES;

    const float *AS[5], *AD[5], *BI[5];
    W5 w5;
    for (int l = 0; l < 5; ++l) {
        w5.p[l] = (const float*)d_in[2 + l * 4 + 0];
        AS[l] = (const float*)d_in[2 + l * 4 + 1];
        AD[l] = (const float*)d_in[2 + l * 4 + 2];
        BI[l] = (const float*)d_in[2 + l * 4 + 3];
    }

    // workspace carve-up
    const size_t PSTRIDE = (size_t)N_PAD * 256;           // elements per plane
    _Float16* planes = (_Float16*)d_ws;                   // GEMM A planes (2, k-tiled)
    float* hbuf = (float*)(planes + 2 * PSTRIDE);         // h f32 [N][256] (layer4: [N][40])
    float* asn  = hbuf + (size_t)N_NODES * 256;
    float* adn  = asn + (size_t)N_NODES * HEADS;
    float* avec0 = adn + (size_t)N_NODES * HEADS;         // [4][64]
    float* dvec0 = avec0 + 256;
    int* rowptr = (int*)(dvec0 + 256);                    // N+1
    int* cursor = rowptr + (N_NODES + 1);
    int* col    = cursor + N_NODES;                       // E + N
    _Float16* wt = (_Float16*)(((uintptr_t)(col + N_EDGES + N_NODES) + 15) & ~(uintptr_t)15);

    // --- CSR build ---
    init_deg_kernel<<<(N_NODES + 255) / 256, 256, 0, stream>>>(cursor);
    hist_kernel<<<(N_EDGES + 255) / 256, 256, 0, stream>>>(dst, cursor);
    scan_kernel<<<1, 1024, 0, stream>>>(cursor, rowptr, cursor);
    scatter_kernel<<<(N_EDGES + N_NODES + 255) / 256, 256, 0, stream>>>(src, dst, cursor, col);

    // --- weight split (layer-0 block-diag) + layer-0 attention vectors ---
    w_split_kernel<<<5 * 65536 / 256, 256, 0, stream>>>(w5, wt);
    avec0_kernel<<<1, 256, 0, stream>>>(w5.p[0], AS[0], AD[0], avec0, dvec0);
    attn0_kernel<<<(N_NODES * HEADS + 255) / 256, 256, 0, stream>>>(
        x_in, avec0, dvec0, asn, adn);

    // --- layer 0: aggregate x0 (64-dim), then block-diag GEMM ---
    aggregate_x0_kernel<<<N_NODES / 4, 256, 0, stream>>>(
        x_in, asn, adn, rowptr, col, planes, PSTRIDE);
    {
        dim3 ggrid(N_PAD / 128, 2);
        gemm_mfma_kernel<3><<<ggrid, 256, 0, stream>>>(
            planes, PSTRIDE, wt, nullptr, 256, 256,
            nullptr, nullptr, nullptr, nullptr, BI[0], planes, PSTRIDE);
    }

    // --- layers 1-4 ---
    for (int l = 1; l < 5; ++l) {
        const int NC = (l == 4) ? 40 : 256;
        dim3 ggrid(N_PAD / 128, (NC + 127) / 128);
        const _Float16* wl = wt + (size_t)l * 131072;
        if (l < 4) {
            gemm_mfma_kernel<1><<<ggrid, 256, 0, stream>>>(
                planes, PSTRIDE, wl, hbuf, 256, NC, AS[l], AD[l], asn, adn,
                nullptr, nullptr, 0);
            aggregate64_kernel<<<N_NODES / 4, 256, 0, stream>>>(
                hbuf, asn, adn, rowptr, col, BI[l], planes, PSTRIDE);
        } else {
            gemm_mfma_kernel<2><<<ggrid, 256, 0, stream>>>(
                planes, PSTRIDE, wl, hbuf, 256, NC, AS[l], AD[l], asn, adn,
                nullptr, nullptr, 0);
            aggregate_out10_kernel<<<N_NODES / 4, 256, 0, stream>>>(
                hbuf, asn, adn, rowptr, col, BI[l], (float*)d_out);
        }
    }
    (void)in_sizes; (void)n_in; (void)out_size; (void)ws_size;
}